// Round 4
// baseline (613.015 us; speedup 1.0000x reference)
//
#include <hip/hip_runtime.h>
#include <stdint.h>

// Problem constants
#define BS 6
#define NQ 4096
#define NH 8
#define EMB 256
#define LTOT 19560
#define ROWS_V 117360
#define ROWS_VP 117376          // 917*128
#define ROWS_Q 24576            // 192*128

typedef __attribute__((ext_vector_type(8))) short bf16x8;
typedef __attribute__((ext_vector_type(4))) float floatx4;

__device__ __forceinline__ ushort f2bf(float f) {
    union { float f; uint32_t i; } c; c.f = f;
    uint32_t r = c.i + 0x7FFFu + ((c.i >> 16) & 1u);   // RNE
    return (ushort)(r >> 16);
}
// pack two fp32 -> two bf16 (round-half-up ~ RNE), 3 insts
__device__ __forceinline__ uint32_t pk2bf(float x, float y) {
    union { float f; uint32_t i; } a, b; a.f = x; b.f = y;
    return __builtin_amdgcn_perm(b.i + 0x8000u, a.i + 0x8000u, 0x07060302u);
}

__device__ __forceinline__ void gll16(const void* g, void* l) {
    __builtin_amdgcn_global_load_lds(
        (const __attribute__((address_space(1))) void*)g,
        (__attribute__((address_space(3))) void*)l, 16, 0, 0);
}

#define PFMA4(d, s, v) \
    (d).x = fmaf((s), (v).x, (d).x); \
    (d).y = fmaf((s), (v).y, (d).y); \
    (d).z = fmaf((s), (v).z, (d).z); \
    (d).w = fmaf((s), (v).w, (d).w);

// ---------------------------------------------------------------------------
// W (K=256 x N) fp32 -> Wt chunked bf16:
// Wt[nb*(NB*256) + (c*NB + nl)*32 + kp] = bf16(W[(c*32+kp)*N + nb*NB + nl])
// ---------------------------------------------------------------------------
__global__ __launch_bounds__(256) void cast_tc(
    const float* __restrict__ W, ushort* __restrict__ Wt, int N_, int lgNB)
{
    int id = blockIdx.x * 256 + threadIdx.x;
    if (id >= 256 * N_) return;
    int nb   = id >> (8 + lgNB);
    int rem  = id & ((256 << lgNB) - 1);
    int c    = rem >> (5 + lgNB);
    int rem2 = rem & ((32 << lgNB) - 1);
    int nl   = rem2 >> 5;
    int kp   = rem2 & 31;
    int k = (c << 5) + kp;
    int n = (nb << lgNB) + nl;
    Wt[id] = f2bf(W[(size_t)k * N_ + n]);
}

// chunked concat of W_off (256x512) and W_attn (256x256) into 768 cols, NB=256
__global__ __launch_bounds__(256) void cast_wq(
    const float* __restrict__ W_off, const float* __restrict__ W_attn,
    ushort* __restrict__ Wt)
{
    int id = blockIdx.x * 256 + threadIdx.x;      // [0, 768*256)
    int nb   = id >> 16;
    int rem  = id & 65535;
    int c    = rem >> 13;
    int rem2 = rem & 8191;
    int nl   = rem2 >> 5;
    int kp   = rem2 & 31;
    int k = (c << 5) + kp;
    int n = (nb << 8) + nl;
    float s = (n < 512) ? W_off[(size_t)k * 512 + n]
                        : W_attn[(size_t)k * 256 + (n - 512)];
    Wt[id] = f2bf(s);
}

__global__ __launch_bounds__(768) void bias_concat(
    const float* __restrict__ b_off, const float* __restrict__ b_attn,
    float* __restrict__ bcat)
{
    int i = threadIdx.x;
    bcat[i] = (i < 512) ? b_off[i] : b_attn[i - 512];
}

// ---------------------------------------------------------------------------
// Barrier-free GEMM, fp32 A: C[M, ldc-sub 256] = A[M,256] @ B^T + bias
// Block: 512 thr = 8 waves (2m x 4n). Tile 128(M) x 256(N). All of B (chunked
// 128 KB) staged to LDS once; A fragments direct global->reg with bf16 cvt.
// ---------------------------------------------------------------------------
__global__ __launch_bounds__(512) void gemm_f32a(
    const float* __restrict__ A,     // M x 256 fp32
    const ushort* __restrict__ Bt,   // chunked 256x256 block (128 KB)
    const float* __restrict__ bias,  // 256
    float* __restrict__ C,           // M x ldc fp32 (pre-offset to col block)
    int M, int ldc)
{
    __shared__ ushort Bs[256 * 256];   // 128 KB, chunked (c*256+n)*32+kp

    const int t = threadIdx.x;
    const int w = t >> 6;
    const int lane = t & 63;
    const int bm = blockIdx.x * 128;
    const int wm = (w >> 2) * 64;
    const int wn = (w & 3) * 64;

    // stage all of B: 16 steps x 512 thr x 16 B
    {
        const char* gsrc = (const char*)Bt + t * 16;
        char* ldst = (char*)Bs + t * 16;
        #pragma unroll
        for (int s = 0; s < 16; ++s)
            gll16(gsrc + s * 8192, ldst + s * 8192);
    }

    const int ml = lane & 15;
    const int kq = lane >> 4;          // k-quarter: 8 floats = 32 B

    // A row base pointers for i = 0..3
    const float* Ar[4];
    bool rok[4];
    #pragma unroll
    for (int i = 0; i < 4; ++i) {
        int row = bm + wm + i * 16 + ml;
        rok[i] = row < M;
        Ar[i] = A + (size_t)row * 256 + kq * 8;
    }

    floatx4 acc[4][4] = {};
    __syncthreads();   // B staged (drains vmcnt)

    #pragma unroll
    for (int c = 0; c < 8; ++c) {
        bf16x8 a[4], b[4];
        #pragma unroll
        for (int i = 0; i < 4; ++i) {
            float4 f0, f1;
            if (rok[i]) {
                f0 = *(const float4*)(Ar[i] + c * 32);
                f1 = *(const float4*)(Ar[i] + c * 32 + 4);
            } else {
                f0 = make_float4(0.f, 0.f, 0.f, 0.f); f1 = f0;
            }
            union { uint32_t u[4]; bf16x8 v; } pk;
            pk.u[0] = pk2bf(f0.x, f0.y);
            pk.u[1] = pk2bf(f0.z, f0.w);
            pk.u[2] = pk2bf(f1.x, f1.y);
            pk.u[3] = pk2bf(f1.z, f1.w);
            a[i] = pk.v;
        }
        #pragma unroll
        for (int j = 0; j < 4; ++j)
            b[j] = *(const bf16x8*)&Bs[(c * 256 + wn + j * 16 + ml) * 32 + kq * 8];
        #pragma unroll
        for (int i = 0; i < 4; ++i)
            #pragma unroll
            for (int j = 0; j < 4; ++j)
                acc[i][j] = __builtin_amdgcn_mfma_f32_16x16x32_bf16(
                    a[i], b[j], acc[i][j], 0, 0, 0);
    }

    const int crow = (lane >> 4) * 4;
    const int ccol = lane & 15;
    #pragma unroll
    for (int j = 0; j < 4; ++j) {
        int gcol = wn + j * 16 + ccol;
        float bv = bias[gcol];
        #pragma unroll
        for (int i = 0; i < 4; ++i) {
            #pragma unroll
            for (int r = 0; r < 4; ++r) {
                int grow = bm + wm + i * 16 + crow + r;
                if (grow < M)
                    C[(size_t)grow * ldc + gcol] = acc[i][j][r] + bv;
            }
        }
    }
}

// ---------------------------------------------------------------------------
// Barrier-free GEMM, bf16 A: tile 128(M) x 128(N), 256 thr = 4 waves (2x2).
// B chunk (64 KB) in LDS; A fragments direct global->reg (already bf16).
// ---------------------------------------------------------------------------
__global__ __launch_bounds__(256) void gemm_bf16a(
    const ushort* __restrict__ A,    // M x 256 bf16
    const ushort* __restrict__ Bt,   // chunked 128x256 block (64 KB)
    const float* __restrict__ bias,  // 128
    float* __restrict__ C,           // M x ldc fp32 (pre-offset to col block)
    int M, int ldc)
{
    __shared__ ushort Bs[128 * 256];   // 64 KB, chunked (c*128+n)*32+kp

    const int t = threadIdx.x;
    const int w = t >> 6;
    const int lane = t & 63;
    const int bm = blockIdx.x * 128;
    const int wm = (w >> 1) * 64;
    const int wn = (w & 1) * 64;

    {
        const char* gsrc = (const char*)Bt + t * 16;
        char* ldst = (char*)Bs + t * 16;
        #pragma unroll
        for (int s = 0; s < 16; ++s)
            gll16(gsrc + s * 4096, ldst + s * 4096);
    }

    const int ml = lane & 15;
    const int kq = lane >> 4;

    const ushort* Ar[4];
    bool rok[4];
    #pragma unroll
    for (int i = 0; i < 4; ++i) {
        int row = bm + wm + i * 16 + ml;
        rok[i] = row < M;
        Ar[i] = A + (size_t)row * 256 + kq * 8;
    }

    floatx4 acc[4][4] = {};
    __syncthreads();

    #pragma unroll
    for (int c = 0; c < 8; ++c) {
        bf16x8 a[4], b[4];
        #pragma unroll
        for (int i = 0; i < 4; ++i) {
            if (rok[i]) a[i] = *(const bf16x8*)(Ar[i] + c * 32);
            else        a[i] = bf16x8{0,0,0,0,0,0,0,0};
        }
        #pragma unroll
        for (int j = 0; j < 4; ++j)
            b[j] = *(const bf16x8*)&Bs[(c * 128 + wn + j * 16 + ml) * 32 + kq * 8];
        #pragma unroll
        for (int i = 0; i < 4; ++i)
            #pragma unroll
            for (int j = 0; j < 4; ++j)
                acc[i][j] = __builtin_amdgcn_mfma_f32_16x16x32_bf16(
                    a[i], b[j], acc[i][j], 0, 0, 0);
    }

    const int crow = (lane >> 4) * 4;
    const int ccol = lane & 15;
    #pragma unroll
    for (int j = 0; j < 4; ++j) {
        int gcol = wn + j * 16 + ccol;
        float bv = bias[gcol];
        #pragma unroll
        for (int i = 0; i < 4; ++i) {
            #pragma unroll
            for (int r = 0; r < 4; ++r) {
                int grow = bm + wm + i * 16 + crow + r;
                if (grow < M)
                    C[(size_t)grow * ldc + gcol] = acc[i][j][r] + bv;
            }
        }
    }
}

// ---------------------------------------------------------------------------
// Deformable sampling: fp32 v, fused softmax, precompute + shuffle broadcast.
// 4 lanes per (b,q,h); lane st owns level st (8 points) and channels
// [st*8, st*8+8). Precompute folded weights + clamped indices per point,
// then 32-iteration loop: 8 width-4 shuffles + 4 gathers (32 B) + FMAs.
// ---------------------------------------------------------------------------
__global__ __launch_bounds__(256) void sampler5(
    const float* __restrict__ v,     // (BS, LTOT, 256) fp32
    const float* __restrict__ qp,    // (BS*NQ, 768): [0:512) off, [512:768) logits
    const float* __restrict__ ref,   // (BS*NQ, 4, 2)
    ushort* __restrict__ agg)        // (BS*NQ, 256) bf16
{
    const int tid = threadIdx.x;
    const int g = blockIdx.x * 64 + (tid >> 2);
    const int st = tid & 2 ? (tid & 1 ? 3 : 2) : (tid & 1 ? 1 : 0); // = tid&3
    const int h = g & 7;
    const int bq = g >> 3;
    const int b = bq >> 12;

    // per-lane level constants
    const int W  = (st == 0) ? 160 : (st == 1) ? 80 : (st == 2) ? 40 : 20;
    const int Hh = (st == 0) ? 92  : (st == 1) ? 46 : (st == 2) ? 23 : 12;
    const int S  = (st == 0) ? 0 : (st == 1) ? 14720 : (st == 2) ? 18400 : 19320;
    const float Wf = (float)W, Hf = (float)Hh;

    float2 rf = *(const float2*)(ref + (size_t)bq * 8 + st * 2);

    float o[16];
    {
        const float* offp = qp + (size_t)bq * 768 + h * 64 + st * 16;
        #pragma unroll
        for (int i = 0; i < 4; ++i)
            *(float4*)&o[i * 4] = *(const float4*)(offp + i * 4);
    }
    // fused softmax over 32 logits (8 per lane, width-4 group)
    float a8[8];
    {
        const float* lp = qp + (size_t)bq * 768 + 512 + h * 32 + st * 8;
        *(float4*)&a8[0] = *(const float4*)(lp);
        *(float4*)&a8[4] = *(const float4*)(lp + 4);
        float m = a8[0];
        #pragma unroll
        for (int i = 1; i < 8; ++i) m = fmaxf(m, a8[i]);
        m = fmaxf(m, __shfl_xor(m, 1, 4));
        m = fmaxf(m, __shfl_xor(m, 2, 4));
        float s = 0.f;
        #pragma unroll
        for (int i = 0; i < 8; ++i) { a8[i] = __expf(a8[i] - m); s += a8[i]; }
        s += __shfl_xor(s, 1, 4);
        s += __shfl_xor(s, 2, 4);
        float inv = 1.f / s;
        #pragma unroll
        for (int i = 0; i < 8; ++i) a8[i] *= inv;
    }

    // precompute folded weights + flat indices for this lane's 8 points
    float w00[8], w10[8], w01[8], w11[8];
    int   i00[8], i10[8], i01[8], i11[8];
    #pragma unroll
    for (int j = 0; j < 8; ++j) {
        float px = fmaf(rf.x, Wf, o[2 * j]) - 0.5f;
        float py = fmaf(rf.y, Hf, o[2 * j + 1]) - 0.5f;
        float x0f = floorf(px), y0f = floorf(py);
        float wx = px - x0f, wy = py - y0f;
        int x0 = (int)x0f, y0 = (int)y0f;
        int x1 = x0 + 1, y1 = y0 + 1;
        float vx0 = (x0 >= 0 && x0 < W) ? 1.f : 0.f;
        float vx1 = (x1 >= 0 && x1 < W) ? 1.f : 0.f;
        float vy0 = (y0 >= 0 && y0 < Hh) ? 1.f : 0.f;
        float vy1 = (y1 >= 0 && y1 < Hh) ? 1.f : 0.f;
        int cx0 = min(max(x0, 0), W - 1);
        int cx1 = min(max(x1, 0), W - 1);
        int cy0 = min(max(y0, 0), Hh - 1);
        int cy1 = min(max(y1, 0), Hh - 1);
        float aj = a8[j];
        w00[j] = (1.f - wx) * (1.f - wy) * vx0 * vy0 * aj;
        w10[j] = wx * (1.f - wy) * vx1 * vy0 * aj;
        w01[j] = (1.f - wx) * wy * vx0 * vy1 * aj;
        w11[j] = wx * wy * vx1 * vy1 * aj;
        i00[j] = S + cy0 * W + cx0;
        i10[j] = S + cy0 * W + cx1;
        i01[j] = S + cy1 * W + cx0;
        i11[j] = S + cy1 * W + cx1;
    }

    const float* vb = v + (size_t)b * LTOT * EMB + h * 32 + st * 8;

    float4 accL = make_float4(0.f, 0.f, 0.f, 0.f);
    float4 accH = make_float4(0.f, 0.f, 0.f, 0.f);

    #pragma unroll
    for (int k = 0; k < 32; ++k) {
        const int own = k >> 3;
        const int j = k & 7;
        float W00 = __shfl(w00[j], own, 4);
        float W10 = __shfl(w10[j], own, 4);
        float W01 = __shfl(w01[j], own, 4);
        float W11 = __shfl(w11[j], own, 4);
        int I00 = __shfl(i00[j], own, 4);
        int I10 = __shfl(i10[j], own, 4);
        int I01 = __shfl(i01[j], own, 4);
        int I11 = __shfl(i11[j], own, 4);

        const float4* p00 = (const float4*)(vb + (size_t)I00 * 256);
        const float4* p10 = (const float4*)(vb + (size_t)I10 * 256);
        const float4* p01 = (const float4*)(vb + (size_t)I01 * 256);
        const float4* p11 = (const float4*)(vb + (size_t)I11 * 256);
        float4 l00 = p00[0], h00 = p00[1];
        float4 l10 = p10[0], h10 = p10[1];
        float4 l01 = p01[0], h01 = p01[1];
        float4 l11 = p11[0], h11 = p11[1];

        PFMA4(accL, W00, l00); PFMA4(accH, W00, h00);
        PFMA4(accL, W10, l10); PFMA4(accH, W10, h10);
        PFMA4(accL, W01, l01); PFMA4(accH, W01, h01);
        PFMA4(accL, W11, l11); PFMA4(accH, W11, h11);
    }

    ushort* ap = agg + (size_t)bq * 256 + h * 32 + st * 8;
    ushort4 r0, r1;
    r0.x = f2bf(accL.x); r0.y = f2bf(accL.y); r0.z = f2bf(accL.z); r0.w = f2bf(accL.w);
    r1.x = f2bf(accH.x); r1.y = f2bf(accH.y); r1.z = f2bf(accH.z); r1.w = f2bf(accH.w);
    *(ushort4*)ap = r0;
    *(ushort4*)(ap + 4) = r1;
}

// ---------------------------------------------------------------------------
// Launch
// ---------------------------------------------------------------------------
extern "C" void kernel_launch(void* const* d_in, const int* in_sizes, int n_in,
                              void* d_out, int out_size, void* d_ws, size_t ws_size,
                              hipStream_t stream) {
    const float* query  = (const float*)d_in[0];
    const float* value  = (const float*)d_in[1];
    const float* refpts = (const float*)d_in[2];
    const float* W_off  = (const float*)d_in[4];
    const float* b_off  = (const float*)d_in[5];
    const float* W_attn = (const float*)d_in[6];
    const float* b_attn = (const float*)d_in[7];
    const float* W_val  = (const float*)d_in[8];
    const float* b_val  = (const float*)d_in[9];
    const float* W_out  = (const float*)d_in[10];
    const float* b_out  = (const float*)d_in[11];
    float* out = (float*)d_out;

    char* ws = (char*)d_ws;
    float*  v_f    = (float*) (ws);                    // 117376x256 f32 = 120,193,024
    float*  qp     = (float*) (ws + 120193024ull);     // 24576x768 f32 =  75,497,472
    ushort* agg_bf = (ushort*)(ws + 195690496ull);     // 24576x256 bf16 = 12,582,912
    ushort* Wvt    = (ushort*)(ws + 208273408ull);     // 131,072 (chunked NB=256)
    ushort* Wq     = (ushort*)(ws + 208404480ull);     // 393,216 (3 blocks NB=256)
    ushort* Wot    = (ushort*)(ws + 208797696ull);     // 131,072 (2 blocks NB=128)
    float*  bcat   = (float*) (ws + 208928768ull);     // 3,072

    // weight preprocessing (chunked layouts for linear LDS staging)
    cast_tc<<<256, 256, 0, stream>>>(W_val, Wvt, 256, 8);
    cast_wq<<<768, 256, 0, stream>>>(W_off, W_attn, Wq);
    cast_tc<<<256, 256, 0, stream>>>(W_out, Wot, 256, 7);
    bias_concat<<<1, 768, 0, stream>>>(b_off, b_attn, bcat);

    // 1. v = value @ W_val + b_val -> fp32 (direct fp32 A, barrier-free)
    gemm_f32a<<<ROWS_VP / 128, 512, 0, stream>>>(
        value, Wvt, b_val, v_f, ROWS_V, 256);

    // 2. qp = query @ [W_off | W_attn] + bias (3 column blocks of 256)
    for (int by = 0; by < 3; ++by)
        gemm_f32a<<<ROWS_Q / 128, 512, 0, stream>>>(
            query, Wq + (size_t)by * 65536, bcat + by * 256,
            qp + by * 256, ROWS_Q, 768);

    // 3. sampling + softmax + aggregation -> bf16 agg
    sampler5<<<(ROWS_Q * NH) / 64, 256, 0, stream>>>(
        v_f, qp, refpts, agg_bf);

    // 4. out = agg @ W_out + b_out (2 column blocks of 128)
    for (int by = 0; by < 2; ++by)
        gemm_bf16a<<<ROWS_Q / 128, 256, 0, stream>>>(
            agg_bf, Wot + (size_t)by * 32768, b_out + by * 128,
            out + by * 128, ROWS_Q, 256);
}

// Round 5
// 434.168 us; speedup vs baseline: 1.4119x; 1.4119x over previous
//
#include <hip/hip_runtime.h>
#include <stdint.h>

// Problem constants
#define BS 6
#define NQ 4096
#define NH 8
#define EMB 256
#define LTOT 19560
#define ROWS_V 117360
#define ROWS_VP 117376          // 917*128
#define ROWS_Q 24576            // 192*128

typedef __attribute__((ext_vector_type(8))) short bf16x8;
typedef __attribute__((ext_vector_type(4))) float floatx4;
typedef __attribute__((ext_vector_type(8))) unsigned short ushort8v;

__device__ __forceinline__ ushort f2bf(float f) {
    union { float f; uint32_t i; } c; c.f = f;
    uint32_t r = c.i + 0x7FFFu + ((c.i >> 16) & 1u);   // RNE
    return (ushort)(r >> 16);
}
// pack two fp32 -> packed bf16x2 (round-half-up), 3 insts; low half = x
__device__ __forceinline__ uint32_t pk2bf(float x, float y) {
    union { float f; uint32_t i; } a, b; a.f = x; b.f = y;
    return __builtin_amdgcn_perm(b.i + 0x8000u, a.i + 0x8000u, 0x07060302u);
}
__device__ __forceinline__ float bflo(uint32_t u) {
    union { uint32_t i; float f; } c; c.i = u << 16; return c.f;
}
__device__ __forceinline__ float bfhi(uint32_t u) {
    union { uint32_t i; float f; } c; c.i = u & 0xFFFF0000u; return c.f;
}

__device__ __forceinline__ void gll16(const void* g, void* l) {
    __builtin_amdgcn_global_load_lds(
        (const __attribute__((address_space(1))) void*)g,
        (__attribute__((address_space(3))) void*)l, 16, 0, 0);
}

// ---------------------------------------------------------------------------
// W (K=256 x N) fp32  ->  Wt (N x 256) bf16  (plain row-major N x K)
// ---------------------------------------------------------------------------
__global__ __launch_bounds__(256) void cast_t(
    const float* __restrict__ W, ushort* __restrict__ Wt, int N_)
{
    int id = blockIdx.x * 256 + threadIdx.x;
    if (id >= 256 * N_) return;
    int n = id >> 8;
    int k = id & 255;
    Wt[id] = f2bf(W[(size_t)k * N_ + n]);
}

__global__ __launch_bounds__(768) void bias_concat(
    const float* __restrict__ b_off, const float* __restrict__ b_attn,
    float* __restrict__ bcat)
{
    int i = threadIdx.x;
    bcat[i] = (i < 512) ? b_off[i] : b_attn[i - 512];
}

// ---------------------------------------------------------------------------
// fp32-A MFMA GEMM with A-register prefetch (m97-shape, BK=32, proven LDS
// layout). C[M x ldc] col-block at bn = blockIdx.y*128.
// 256 thr = 4 waves (2m x 2n); tile 128(M) x 128(N).
// A: fp32 global -> regs (prefetched one iter ahead) -> packed bf16 -> LDS.
// B: bf16 (N x 256 row-major), staged via global_load_lds.
// ---------------------------------------------------------------------------
template<bool OUT_BF16>
__global__ __launch_bounds__(256) void gemm_qv(
    const float* __restrict__ A,     // M x 256 fp32
    const ushort* __restrict__ Bt,   // N x 256 bf16
    const float* __restrict__ bias,  // N
    void* __restrict__ Cv,           // M x ldc
    int M, int ldc)
{
    constexpr int K = 256;
    __shared__ ushort As[128 * 32];
    __shared__ ushort Bs[128 * 32];

    const int t = threadIdx.x;
    const int w = t >> 6;
    const int lane = t & 63;
    const int bm = blockIdx.x * 128;
    const int bn = blockIdx.y * 128;
    const int wm = (w >> 1) * 64;
    const int wn = (w & 1) * 64;

    // B staging: wave w stages rows [bn+32w, bn+32w+32) in two 16-row chunks
    const int srow = lane >> 2;
    const int scol = (lane & 3) * 8;
    const ushort* Bg0 = Bt + (size_t)(bn + w * 32 + srow) * K + scol;
    const ushort* Bg1 = Bt + (size_t)(bn + w * 32 + 16 + srow) * K + scol;
    ushort* Bl0 = &Bs[(w * 32) * 32];
    ushort* Bl1 = &Bs[(w * 32 + 16) * 32];

    // A staging: thread t -> row t>>1, cols (t&1)*16 + [0,16)
    const int arow = t >> 1;
    const int acol = (t & 1) * 16;
    const bool rowok = (bm + arow) < M;
    const float* Ap = A + (size_t)(bm + arow) * K + acol;
    ushort* Asw = &As[arow * 32 + acol];

    const ushort* apt = &As[(wm + (lane & 15)) * 32 + (lane >> 4) * 8];
    const ushort* bpt = &Bs[(wn + (lane & 15)) * 32 + (lane >> 4) * 8];

    floatx4 acc[4][4] = {};

    // prefetch A for kt = 0
    float4 c0, c1, c2, c3;
    if (rowok) {
        c0 = *(const float4*)(Ap);
        c1 = *(const float4*)(Ap + 4);
        c2 = *(const float4*)(Ap + 8);
        c3 = *(const float4*)(Ap + 12);
    } else {
        c0 = make_float4(0.f, 0.f, 0.f, 0.f);
        c1 = c0; c2 = c0; c3 = c0;
    }

    for (int kt = 0; kt < K; kt += 32) {
        __syncthreads();            // prev iter's fragment reads done
        gll16(Bg0 + kt, Bl0);
        gll16(Bg1 + kt, Bl1);
        uint4 u0, u1;
        u0.x = pk2bf(c0.x, c0.y); u0.y = pk2bf(c0.z, c0.w);
        u0.z = pk2bf(c1.x, c1.y); u0.w = pk2bf(c1.z, c1.w);
        u1.x = pk2bf(c2.x, c2.y); u1.y = pk2bf(c2.z, c2.w);
        u1.z = pk2bf(c3.x, c3.y); u1.w = pk2bf(c3.z, c3.w);
        *(uint4*)Asw = u0;
        *(uint4*)(Asw + 8) = u1;
        __syncthreads();            // staging visible

        // prefetch next iter's A while MFMAs run
        if (kt + 32 < K && rowok) {
            c0 = *(const float4*)(Ap + kt + 32);
            c1 = *(const float4*)(Ap + kt + 36);
            c2 = *(const float4*)(Ap + kt + 40);
            c3 = *(const float4*)(Ap + kt + 44);
        }

        bf16x8 a[4], b[4];
        #pragma unroll
        for (int i = 0; i < 4; ++i) {
            a[i] = *(const bf16x8*)(apt + i * 16 * 32);
            b[i] = *(const bf16x8*)(bpt + i * 16 * 32);
        }
        #pragma unroll
        for (int i = 0; i < 4; ++i)
            #pragma unroll
            for (int j = 0; j < 4; ++j)
                acc[i][j] = __builtin_amdgcn_mfma_f32_16x16x32_bf16(
                    a[i], b[j], acc[i][j], 0, 0, 0);
    }

    const int crow = (lane >> 4) * 4;
    const int ccol = lane & 15;
    #pragma unroll
    for (int j = 0; j < 4; ++j) {
        int gcol = bn + wn + j * 16 + ccol;
        float bv = bias[gcol];
        #pragma unroll
        for (int i = 0; i < 4; ++i) {
            #pragma unroll
            for (int r = 0; r < 4; ++r) {
                int grow = bm + wm + i * 16 + crow + r;
                if (grow < M) {
                    float val = acc[i][j][r] + bv;
                    if (OUT_BF16)
                        ((ushort*)Cv)[(size_t)grow * ldc + gcol] = f2bf(val);
                    else
                        ((float*)Cv)[(size_t)grow * ldc + gcol] = val;
                }
            }
        }
    }
}

// ---------------------------------------------------------------------------
// bf16-A MFMA GEMM (round-3 proven, for out-projection)
// ---------------------------------------------------------------------------
__global__ __launch_bounds__(256) void gemm_bt(
    const ushort* __restrict__ A,    // M x 256 bf16
    const ushort* __restrict__ Bt,   // N x 256 bf16
    const float* __restrict__ bias,  // N
    float* __restrict__ C, int M, int N)
{
    constexpr int K = 256;
    __shared__ ushort As[128 * 32];
    __shared__ ushort Bs[128 * 32];

    const int t = threadIdx.x;
    const int w = t >> 6;
    const int lane = t & 63;
    const int bm = blockIdx.x * 128;
    const int bn = blockIdx.y * 128;
    const int wm = (w >> 1) * 64;
    const int wn = (w & 1) * 64;

    floatx4 acc[4][4] = {};

    const int srow = lane >> 2;
    const int scol = (lane & 3) * 8;
    const ushort* Ag0 = A + (size_t)(bm + (w * 2 + 0) * 16 + srow) * K + scol;
    const ushort* Ag1 = A + (size_t)(bm + (w * 2 + 1) * 16 + srow) * K + scol;
    const ushort* Bg0 = Bt + (size_t)(bn + (w * 2 + 0) * 16 + srow) * K + scol;
    const ushort* Bg1 = Bt + (size_t)(bn + (w * 2 + 1) * 16 + srow) * K + scol;
    ushort* Al0 = &As[(w * 2 + 0) * 512];
    ushort* Al1 = &As[(w * 2 + 1) * 512];
    ushort* Bl0 = &Bs[(w * 2 + 0) * 512];
    ushort* Bl1 = &Bs[(w * 2 + 1) * 512];

    const ushort* apt = &As[(wm + (lane & 15)) * 32 + (lane >> 4) * 8];
    const ushort* bpt = &Bs[(wn + (lane & 15)) * 32 + (lane >> 4) * 8];

    for (int kt = 0; kt < K; kt += 32) {
        __syncthreads();
        gll16(Ag0 + kt, Al0);
        gll16(Ag1 + kt, Al1);
        gll16(Bg0 + kt, Bl0);
        gll16(Bg1 + kt, Bl1);
        __syncthreads();

        bf16x8 a[4], b[4];
        #pragma unroll
        for (int i = 0; i < 4; ++i) {
            a[i] = *(const bf16x8*)(apt + i * 16 * 32);
            b[i] = *(const bf16x8*)(bpt + i * 16 * 32);
        }
        #pragma unroll
        for (int i = 0; i < 4; ++i)
            #pragma unroll
            for (int j = 0; j < 4; ++j)
                acc[i][j] = __builtin_amdgcn_mfma_f32_16x16x32_bf16(
                    a[i], b[j], acc[i][j], 0, 0, 0);
    }

    const int crow = (lane >> 4) * 4;
    const int ccol = lane & 15;
    #pragma unroll
    for (int j = 0; j < 4; ++j) {
        int gcol = bn + wn + j * 16 + ccol;
        float bv = bias[gcol];
        #pragma unroll
        for (int i = 0; i < 4; ++i) {
            #pragma unroll
            for (int r = 0; r < 4; ++r) {
                int grow = bm + wm + i * 16 + crow + r;
                if (grow < M)
                    C[(size_t)grow * N + gcol] = acc[i][j][r] + bv;
            }
        }
    }
}

// ---------------------------------------------------------------------------
// Deformable sampling: bf16 v, fused softmax, precompute + shuffle broadcast.
// 4 lanes per (b,q,h); lane st owns level st (8 points) and channels
// [st*8, st*8+8). Precompute folded weights + clamped flat indices per point,
// then the 32-point loop is 8 width-4 shuffles + 4 16B gathers + unpack-FMAs.
// ---------------------------------------------------------------------------
__global__ __launch_bounds__(256) void sampler6(
    const ushort* __restrict__ v,    // (BS, LTOT, 256) bf16
    const float* __restrict__ qp,    // (BS*NQ, 768): [0:512) off, [512:768) logits
    const float* __restrict__ ref,   // (BS*NQ, 4, 2)
    ushort* __restrict__ agg)        // (BS*NQ, 256) bf16
{
    const int tid = threadIdx.x;
    const int g = blockIdx.x * 64 + (tid >> 2);
    const int st = tid & 3;
    const int h = g & 7;
    const int bq = g >> 3;
    const int b = bq >> 12;

    // per-lane level constants
    const int W  = (st == 0) ? 160 : (st == 1) ? 80 : (st == 2) ? 40 : 20;
    const int Hh = (st == 0) ? 92  : (st == 1) ? 46 : (st == 2) ? 23 : 12;
    const int S  = (st == 0) ? 0 : (st == 1) ? 14720 : (st == 2) ? 18400 : 19320;
    const float Wf = (float)W, Hf = (float)Hh;

    float2 rf = *(const float2*)(ref + (size_t)bq * 8 + st * 2);

    float o[16];
    {
        const float* offp = qp + (size_t)bq * 768 + h * 64 + st * 16;
        #pragma unroll
        for (int i = 0; i < 4; ++i)
            *(float4*)&o[i * 4] = *(const float4*)(offp + i * 4);
    }
    // fused softmax over 32 logits (8 per lane, width-4 group)
    float a8[8];
    {
        const float* lp = qp + (size_t)bq * 768 + 512 + h * 32 + st * 8;
        *(float4*)&a8[0] = *(const float4*)(lp);
        *(float4*)&a8[4] = *(const float4*)(lp + 4);
        float m = a8[0];
        #pragma unroll
        for (int i = 1; i < 8; ++i) m = fmaxf(m, a8[i]);
        m = fmaxf(m, __shfl_xor(m, 1, 4));
        m = fmaxf(m, __shfl_xor(m, 2, 4));
        float s = 0.f;
        #pragma unroll
        for (int i = 0; i < 8; ++i) { a8[i] = __expf(a8[i] - m); s += a8[i]; }
        s += __shfl_xor(s, 1, 4);
        s += __shfl_xor(s, 2, 4);
        float inv = 1.f / s;
        #pragma unroll
        for (int i = 0; i < 8; ++i) a8[i] *= inv;
    }

    // precompute folded weights + flat indices for this lane's level (8 pts)
    float w00[8], w10[8], w01[8], w11[8];
    int   i00[8], i10[8], i01[8], i11[8];
    #pragma unroll
    for (int j = 0; j < 8; ++j) {
        float px = fmaf(rf.x, Wf, o[2 * j]) - 0.5f;
        float py = fmaf(rf.y, Hf, o[2 * j + 1]) - 0.5f;
        float x0f = floorf(px), y0f = floorf(py);
        float wx = px - x0f, wy = py - y0f;
        int x0 = (int)x0f, y0 = (int)y0f;
        int x1 = x0 + 1, y1 = y0 + 1;
        float vx0 = (x0 >= 0 && x0 < W) ? 1.f : 0.f;
        float vx1 = (x1 >= 0 && x1 < W) ? 1.f : 0.f;
        float vy0 = (y0 >= 0 && y0 < Hh) ? 1.f : 0.f;
        float vy1 = (y1 >= 0 && y1 < Hh) ? 1.f : 0.f;
        int cx0 = min(max(x0, 0), W - 1);
        int cx1 = min(max(x1, 0), W - 1);
        int cy0 = min(max(y0, 0), Hh - 1);
        int cy1 = min(max(y1, 0), Hh - 1);
        float aj = a8[j];
        w00[j] = (1.f - wx) * (1.f - wy) * vx0 * vy0 * aj;
        w10[j] = wx * (1.f - wy) * vx1 * vy0 * aj;
        w01[j] = (1.f - wx) * wy * vx0 * vy1 * aj;
        w11[j] = wx * wy * vx1 * vy1 * aj;
        i00[j] = S + cy0 * W + cx0;
        i10[j] = S + cy0 * W + cx1;
        i01[j] = S + cy1 * W + cx0;
        i11[j] = S + cy1 * W + cx1;
    }

    const ushort* vb = v + (size_t)b * LTOT * EMB + h * 32 + st * 8;

    float acc[8] = {0.f, 0.f, 0.f, 0.f, 0.f, 0.f, 0.f, 0.f};

    #pragma unroll
    for (int k = 0; k < 32; ++k) {
        const int own = k >> 3;
        const int j = k & 7;
        float W00 = __shfl(w00[j], own, 4);
        float W10 = __shfl(w10[j], own, 4);
        float W01 = __shfl(w01[j], own, 4);
        float W11 = __shfl(w11[j], own, 4);
        int I00 = __shfl(i00[j], own, 4);
        int I10 = __shfl(i10[j], own, 4);
        int I01 = __shfl(i01[j], own, 4);
        int I11 = __shfl(i11[j], own, 4);

        uint4 c00 = *(const uint4*)(vb + (size_t)I00 * EMB);
        uint4 c10 = *(const uint4*)(vb + (size_t)I10 * EMB);
        uint4 c01 = *(const uint4*)(vb + (size_t)I01 * EMB);
        uint4 c11 = *(const uint4*)(vb + (size_t)I11 * EMB);

        #define ACC8(w_, c_) \
            acc[0] = fmaf(w_, bflo(c_.x), acc[0]); acc[1] = fmaf(w_, bfhi(c_.x), acc[1]); \
            acc[2] = fmaf(w_, bflo(c_.y), acc[2]); acc[3] = fmaf(w_, bfhi(c_.y), acc[3]); \
            acc[4] = fmaf(w_, bflo(c_.z), acc[4]); acc[5] = fmaf(w_, bfhi(c_.z), acc[5]); \
            acc[6] = fmaf(w_, bflo(c_.w), acc[6]); acc[7] = fmaf(w_, bfhi(c_.w), acc[7]);
        ACC8(W00, c00);
        ACC8(W10, c10);
        ACC8(W01, c01);
        ACC8(W11, c11);
        #undef ACC8
    }

    ushort8v r;
    #pragma unroll
    for (int i = 0; i < 8; ++i) r[i] = f2bf(acc[i]);
    *(ushort8v*)(agg + (size_t)bq * 256 + h * 32 + st * 8) = r;
}

// ---------------------------------------------------------------------------
// Launch
// ---------------------------------------------------------------------------
extern "C" void kernel_launch(void* const* d_in, const int* in_sizes, int n_in,
                              void* d_out, int out_size, void* d_ws, size_t ws_size,
                              hipStream_t stream) {
    const float* query  = (const float*)d_in[0];
    const float* value  = (const float*)d_in[1];
    const float* refpts = (const float*)d_in[2];
    const float* W_off  = (const float*)d_in[4];
    const float* b_off  = (const float*)d_in[5];
    const float* W_attn = (const float*)d_in[6];
    const float* b_attn = (const float*)d_in[7];
    const float* W_val  = (const float*)d_in[8];
    const float* b_val  = (const float*)d_in[9];
    const float* W_out  = (const float*)d_in[10];
    const float* b_out  = (const float*)d_in[11];
    float* out = (float*)d_out;

    char* ws = (char*)d_ws;
    ushort* v_bf   = (ushort*)(ws);                     // 117376x256 bf16 = 60,096,512
    float*  qp     = (float*) (ws + 60096512ull);       // 24576x768 f32  = 75,497,472
    ushort* agg_bf = (ushort*)(ws + 135593984ull);      // 24576x256 bf16 = 12,582,912
    ushort* Wvt    = (ushort*)(ws + 148176896ull);      // 256x256 bf16 = 131,072
    ushort* Wq     = (ushort*)(ws + 148307968ull);      // 768x256 bf16 = 393,216
    ushort* Wot    = (ushort*)(ws + 148701184ull);      // 256x256 bf16 = 131,072
    float*  bcat   = (float*) (ws + 148832256ull);      // 3,072

    // weight preprocessing (plain N x K transposed bf16)
    cast_t<<<256, 256, 0, stream>>>(W_val, Wvt, 256);
    cast_t<<<512, 256, 0, stream>>>(W_off, Wq, 512);
    cast_t<<<256, 256, 0, stream>>>(W_attn, Wq + 512 * 256, 256);
    cast_t<<<256, 256, 0, stream>>>(W_out, Wot, 256);
    bias_concat<<<1, 768, 0, stream>>>(b_off, b_attn, bcat);

    // 1. v = value @ W_val + b_val -> bf16 (fp32 A direct, reg-prefetch)
    gemm_qv<true><<<dim3(ROWS_VP / 128, 2), 256, 0, stream>>>(
        value, Wvt, b_val, v_bf, ROWS_V, 256);

    // 2. qp = query @ [W_off | W_attn] + bias (fp32 A direct, N=768)
    gemm_qv<false><<<dim3(ROWS_Q / 128, 6), 256, 0, stream>>>(
        query, Wq, bcat, qp, ROWS_Q, 768);

    // 3. sampling + softmax + aggregation -> bf16 agg
    sampler6<<<(ROWS_Q * NH) / 64, 256, 0, stream>>>(
        v_bf, qp, refpts, agg_bf);

    // 4. out = agg @ W_out + b_out
    gemm_bt<<<dim3(ROWS_Q / 128, 2), 256, 0, stream>>>(
        agg_bf, Wot, b_out, out, ROWS_Q, 256);
}